// Round 8
// baseline (1002.693 us; speedup 1.0000x reference)
//
#include <hip/hip_runtime.h>
#include <math.h>

// Problem constants: N=20000, E=320000, C=64, NS=4, NB=8, NH=64
#define PI_F        3.14159265358979323846f
#define SQRT2_F     1.41421356237309515f
#define SQRT3_F     1.73205080756887729f
#define INV_SQRT3_F 0.57735026918962576f
#define INV_AVG     0.25f   // 1/sqrt(16)

#define N_NODES 20000
#define N_EDGES 320000
#define NPERM_SLOTS 20064   // 20000 + 4*7 pad, 8-aligned segments, 32-divisible

typedef _Float16 f16x8 __attribute__((ext_vector_type(8)));
typedef float    f32x4 __attribute__((ext_vector_type(4)));
union HF8 { int4 i; f16x8 v; };
union HF  { _Float16 h; unsigned short u; };

__device__ __forceinline__ float swish_f(float x) {
    return x / (1.f + __expf(-x));
}
__device__ __forceinline__ unsigned short f2h(float f) {
    HF x; x.h = (_Float16)f; return x.u;
}

// ---------------------------------------------------------------------------
// Prologue: pack W_mlp2 (64x256) into fp16 MFMA B-fragment layout.
// Slot = kt*16+NT (32 slots), pos = lane*8+j, value = W2[k][n] with
// k = kt*32 + (lane>>4)*8 + j, n = NT*16 + (lane&15).
// ---------------------------------------------------------------------------
__global__ __launch_bounds__(256) void k_prep_w(
    const float* __restrict__ W2, unsigned short* __restrict__ W2p)
{
    const int t2 = blockIdx.x * 256 + threadIdx.x;   // 64*256 = 16384
    const int j = t2 & 7, l = (t2 >> 3) & 63, slot = t2 >> 9;   // 0..31
    const int kt = slot >> 4, NT = slot & 15;
    const int k = kt*32 + ((l >> 4) << 3) + j, n = NT*16 + (l & 15);
    W2p[t2] = f2h(W2[k*256 + n]);
}

// ---------------------------------------------------------------------------
// Edge counting sort by receiver (known good).
// ---------------------------------------------------------------------------
__global__ __launch_bounds__(256) void k_zero_cnt(int* __restrict__ cnt) {
    const int i = blockIdx.x * 256 + threadIdx.x;
    if (i < N_NODES) cnt[i] = 0;
}
__global__ __launch_bounds__(256) void k_hist(const int* __restrict__ rcv,
                                              int* __restrict__ cnt) {
    const int e = blockIdx.x * 256 + threadIdx.x;
    if (e < N_EDGES) atomicAdd(&cnt[rcv[e]], 1);
}
__global__ __launch_bounds__(1024) void k_scan(const int* __restrict__ cnt,
                                               int* __restrict__ cursor) {
    __shared__ int part[1024];
    const int t = threadIdx.x;
    const int base = t * 20;
    int s = 0;
    #pragma unroll
    for (int j = 0; j < 20; ++j) {
        const int idx = base + j;
        if (idx < N_NODES) s += cnt[idx];
    }
    part[t] = s;
    __syncthreads();
    for (int d = 1; d < 1024; d <<= 1) {
        const int v = (t >= d) ? part[t - d] : 0;
        __syncthreads();
        part[t] += v;
        __syncthreads();
    }
    int run = (t == 0) ? 0 : part[t - 1];
    for (int j = 0; j < 20; ++j) {
        const int idx = base + j;
        if (idx < N_NODES) { cursor[idx] = run; run += cnt[idx]; }
    }
}
__global__ __launch_bounds__(256) void k_scatter(const int* __restrict__ rcv,
                                                 int* __restrict__ cursor,
                                                 int* __restrict__ perm) {
    const int e = blockIdx.x * 256 + threadIdx.x;
    if (e < N_EDGES) {
        const int pos = atomicAdd(&cursor[rcv[e]], 1);
        perm[pos] = e;
    }
}

// ---------------------------------------------------------------------------
// Specie sort for node_down (runs AFTER k_edge; nperm aliases dead perm).
// 8-aligned segments, dummies = -1 at tails.
// ---------------------------------------------------------------------------
__global__ __launch_bounds__(256) void k_spec_init(int* __restrict__ nperm,
                                                   int* __restrict__ scnt) {
    const int i = blockIdx.x * 256 + threadIdx.x;
    if (i < NPERM_SLOTS) nperm[i] = -1;
    if (i < 4) scnt[i] = 0;
}
__global__ __launch_bounds__(256) void k_spec_hist(const int* __restrict__ spec,
                                                   int* __restrict__ scnt) {
    const int i = blockIdx.x * 256 + threadIdx.x;
    if (i < N_NODES) atomicAdd(&scnt[spec[i]], 1);
}
__global__ __launch_bounds__(64) void k_spec_off(const int* __restrict__ scnt,
                                                 int* __restrict__ scur) {
    if (threadIdx.x == 0) {
        int off = 0;
        for (int s = 0; s < 4; ++s) { scur[s] = off; off += (scnt[s] + 7) & ~7; }
    }
}
__global__ __launch_bounds__(256) void k_spec_scatter(const int* __restrict__ spec,
                                                      int* __restrict__ scur,
                                                      int* __restrict__ nperm) {
    const int i = blockIdx.x * 256 + threadIdx.x;
    if (i < N_NODES) {
        const int pos = atomicAdd(&scur[spec[i]], 1);
        nperm[pos] = i;
    }
}

// ---------------------------------------------------------------------------
// K1: node up-projection + agg zero-init (known good).
// ---------------------------------------------------------------------------
__global__ __launch_bounds__(256) void k_node_up(
    const float* __restrict__ ns, const float* __restrict__ nv,
    const float* __restrict__ Wus, const float* __restrict__ Wuv,
    float* __restrict__ s_up, float* __restrict__ v_up,
    float* __restrict__ agg_s, float* __restrict__ agg_v)
{
    const int lane = threadIdx.x & 63;
    const int wq   = __builtin_amdgcn_readfirstlane(threadIdx.x >> 6);
    const int n    = blockIdx.x * 4 + wq;

    const float* nsr = ns + n * 64;
    const float* nvr = nv + n * 192;
    float acc = 0.f, a0 = 0.f, a1 = 0.f, a2 = 0.f;
    for (int i = 0; i < 64; ++i) {
        const float s = nsr[i];
        acc = fmaf(s, Wus[i*64 + lane], acc);
        const float wv = Wuv[i*64 + lane];
        a0 = fmaf(nvr[i*3+0], wv, a0);
        a1 = fmaf(nvr[i*3+1], wv, a1);
        a2 = fmaf(nvr[i*3+2], wv, a2);
    }
    s_up[n*64 + lane] = acc;
    v_up[(n*64 + lane)*3 + 0] = a0;
    v_up[(n*64 + lane)*3 + 1] = a1;
    v_up[(n*64 + lane)*3 + 2] = a2;

    agg_s[n*128 + lane]      = 0.f;
    agg_s[n*128 + 64 + lane] = 0.f;
    #pragma unroll
    for (int k = 0; k < 6; ++k) agg_v[n*384 + k*64 + lane] = 0.f;
}

// ---------------------------------------------------------------------------
// K2 v8 == v7 (numerics verified: absmax 0.797 = fp16 rounding level).
//  A1: bessel+W0 -> h1v (f32, [le][i] stride 69), own-wave rows.
//  A2: h2 = swish(h1@W1) f32 VALU -> h2h fp16, plain padded [m][i] stride 72,
//      m = ((t&12)<<2)+(wq<<2)+(t&3) (MFMA row for edge le = wq*16+t).
//  B : mix = h2 @ W2 via mfma_f32_16x16x32_f16; A-frags one ds_read_b128,
//      B-frags from prepacked W2p. accB[mt][ntl][rr] = mix[col=64wq+ntl*16+c]
//      [le=q*16+mt*4+rr], f32 end-to-end into phase C.
//  C : per-q-group segmented register scatter-add (v6-verified).
// ---------------------------------------------------------------------------
__global__ __launch_bounds__(256, 4) void k_edge(
    const float* __restrict__ vecs,
    const int*   __restrict__ snd_idx, const int* __restrict__ rcv_idx,
    const int*   __restrict__ perm,
    const float* __restrict__ W0, const float* __restrict__ W1,
    const unsigned short* __restrict__ W2p,
    const float* __restrict__ s_up, const float* __restrict__ v_up,
    float* __restrict__ agg_s, float* __restrict__ agg_v)
{
    __shared__ float h1v[64*69];                          // f32 [le][i]
    __shared__ __align__(16) unsigned short h2h[64*72];   // f16 [m][i]

    const int tid  = threadIdx.x;
    const int lane = tid & 63;
    const int wq   = __builtin_amdgcn_readfirstlane(tid >> 6);
    const int e0   = blockIdx.x * 64;
    const int c    = lane & 15, q = lane >> 4;

    // --- per-lane metadata for sorted slot e0+lane (all 64 edges) ---
    const int pe_l  = perm[e0 + lane];
    const int rcv_l = rcv_idx[pe_l];
    const int snd_l = snd_idx[pe_l];
    const float vx_l = vecs[pe_l*3+0], vy_l = vecs[pe_l*3+1], vz_l = vecs[pe_l*3+2];
    const float x_l  = sqrtf(vx_l*vx_l + vy_l*vy_l + vz_l*vz_l);
    const float sx_l = (x_l == 0.f) ? 1.f : x_l;
    const float ys_l = SQRT3_F / sx_l;
    const float Y0_l = vx_l * ys_l, Y1_l = vy_l * ys_l, Y2_l = vz_l * ys_l;
    const float msk_l = (x_l == 0.f) ? 0.f : 1.f;

    // ---- A1: bessel + layer0 -> h1v[le][lane], le = wq*16 + t ----
    #pragma unroll 4
    for (int t = 0; t < 16; ++t) {
        const int le = wq*16 + t;
        const float x = __shfl(x_l, le);
        const float sx = (x == 0.f) ? 1.f : x;
        float s1, c1;
        __sincosf(PI_F * x, &s1, &c1);
        const float u  = fminf(x, 1.f);
        const float u2 = u*u, u3 = u2*u;
        const float u6 = u3*u3, u7 = u6*u, u8 = u6*u2;
        const float env  = (x < 1.f) ? (1.f - 28.f*u6 + 48.f*u7 - 21.f*u8) : 0.f;
        const float pref = SQRT2_F * env / sx;
        float h1 = 0.f;
        float sn = s1, snm1 = 0.f;
        const float twoc = 2.f * c1;
        #pragma unroll
        for (int b = 0; b < 8; ++b) {
            h1 = fmaf(pref * sn, W0[b*64 + lane], h1);
            const float snext = fmaf(twoc, sn, -snm1);
            snm1 = sn; sn = snext;
        }
        h1v[le*69 + lane] = swish_f(h1);
    }
    // no barrier: A2 reads only this wave's own rows

    // ---- A2: h2 = swish(h1 @ W1) f32, write fp16 row-permuted ----
    {
        float acc2[16];
        #pragma unroll
        for (int t = 0; t < 16; ++t) acc2[t] = 0.f;
        for (int i = 0; i < 64; ++i) {
            const float w = W1[i*64 + lane];           // coalesced, L1-hot
            #pragma unroll
            for (int t = 0; t < 16; ++t)
                acc2[t] = fmaf(h1v[(wq*16 + t)*69 + i], w, acc2[t]);
        }
        #pragma unroll
        for (int t = 0; t < 16; ++t) {
            const int m = ((t & 12) << 2) + (wq << 2) + (t & 3);
            h2h[m*72 + lane] = f2h(swish_f(acc2[t]));
        }
    }
    __syncthreads();

    // ---- B: mix = h2 @ W2 (MFMA). wave wq owns cols [64wq,64wq+64). ----
    const f32x4 z = {0.f, 0.f, 0.f, 0.f};
    f32x4 accB[4][4] = {{z,z,z,z},{z,z,z,z},{z,z,z,z},{z,z,z,z}};
    #pragma unroll
    for (int kt = 0; kt < 2; ++kt) {
        HF8 a[4];
        #pragma unroll
        for (int mt = 0; mt < 4; ++mt)
            a[mt].i = *(const int4*)(h2h + (mt*16 + c)*72 + kt*32 + q*8);
        #pragma unroll
        for (int ntl = 0; ntl < 4; ++ntl) {
            HF8 b;
            b.i = *(const int4*)(W2p + ((kt*16 + 4*wq + ntl)*64 + lane)*8);
            #pragma unroll
            for (int mt = 0; mt < 4; ++mt)
                accB[mt][ntl] = __builtin_amdgcn_mfma_f32_16x16x32_f16(a[mt].v, b.v, accB[mt][ntl], 0, 0, 0);
        }
    }
    // accB[mt][ntl][rr] = mix[col = wq*64 + ntl*16 + c][le = q*16 + mt*4 + rr]

    // ---- C: per-q-group segmented scatter-add from registers (v6-verified) --
    int cur = -1;
    if (wq == 0) {            // agg_s[:, ntl*16+c] += msv * mix0
        float ra0=0.f, ra1=0.f, ra2=0.f, ra3=0.f;
        #pragma unroll
        for (int t = 0; t < 16; ++t) {
            const int sl  = (lane & 48) + t;
            const int rcv = __shfl(rcv_l, sl);
            const int snd = __shfl(snd_l, sl);
            const float msk = __shfl(msk_l, sl);
            if (rcv != cur) {
                if (cur >= 0) {
                    float* p = agg_s + cur*128 + c;
                    unsafeAtomicAdd(p,      ra0);
                    unsafeAtomicAdd(p + 16, ra1);
                    unsafeAtomicAdd(p + 32, ra2);
                    unsafeAtomicAdd(p + 48, ra3);
                }
                ra0 = ra1 = ra2 = ra3 = 0.f; cur = rcv;
            }
            const int mt = t >> 2, rr = t & 3;
            const float* sp = s_up + snd*64 + c;
            ra0 = fmaf(sp[0],  accB[mt][0][rr] * msk, ra0);
            ra1 = fmaf(sp[16], accB[mt][1][rr] * msk, ra1);
            ra2 = fmaf(sp[32], accB[mt][2][rr] * msk, ra2);
            ra3 = fmaf(sp[48], accB[mt][3][rr] * msk, ra3);
        }
        float* p = agg_s + cur*128 + c;
        unsafeAtomicAdd(p,      ra0);
        unsafeAtomicAdd(p + 16, ra1);
        unsafeAtomicAdd(p + 32, ra2);
        unsafeAtomicAdd(p + 48, ra3);
    } else if (wq == 1) {     // agg_s[:, 64+ntl*16+c] += (mv.Y)/sqrt3 * mix1
        float ra0=0.f, ra1=0.f, ra2=0.f, ra3=0.f;
        #pragma unroll
        for (int t = 0; t < 16; ++t) {
            const int sl  = (lane & 48) + t;
            const int rcv = __shfl(rcv_l, sl);
            const int snd = __shfl(snd_l, sl);
            const float msk = __shfl(msk_l, sl);
            const float Y0 = __shfl(Y0_l, sl), Y1 = __shfl(Y1_l, sl), Y2 = __shfl(Y2_l, sl);
            if (rcv != cur) {
                if (cur >= 0) {
                    float* p = agg_s + cur*128 + 64 + c;
                    unsafeAtomicAdd(p,      ra0);
                    unsafeAtomicAdd(p + 16, ra1);
                    unsafeAtomicAdd(p + 32, ra2);
                    unsafeAtomicAdd(p + 48, ra3);
                }
                ra0 = ra1 = ra2 = ra3 = 0.f; cur = rcv;
            }
            const int mt = t >> 2, rr = t & 3;
            const float* vp = v_up + (snd*64 + c)*3;
            const float t00 = (vp[  0]*Y0 + vp[  1]*Y1 + vp[  2]*Y2) * INV_SQRT3_F;
            const float t01 = (vp[ 48]*Y0 + vp[ 49]*Y1 + vp[ 50]*Y2) * INV_SQRT3_F;
            const float t02 = (vp[ 96]*Y0 + vp[ 97]*Y1 + vp[ 98]*Y2) * INV_SQRT3_F;
            const float t03 = (vp[144]*Y0 + vp[145]*Y1 + vp[146]*Y2) * INV_SQRT3_F;
            ra0 = fmaf(t00, accB[mt][0][rr] * msk, ra0);
            ra1 = fmaf(t01, accB[mt][1][rr] * msk, ra1);
            ra2 = fmaf(t02, accB[mt][2][rr] * msk, ra2);
            ra3 = fmaf(t03, accB[mt][3][rr] * msk, ra3);
        }
        float* p = agg_s + cur*128 + 64 + c;
        unsafeAtomicAdd(p,      ra0);
        unsafeAtomicAdd(p + 16, ra1);
        unsafeAtomicAdd(p + 32, ra2);
        unsafeAtomicAdd(p + 48, ra3);
    } else if (wq == 2) {     // agg_v[:, ntl*16+c, m] += mv_m * mix2
        float rv[4][3];
        #pragma unroll
        for (int i = 0; i < 4; ++i) { rv[i][0]=0.f; rv[i][1]=0.f; rv[i][2]=0.f; }
        #pragma unroll
        for (int t = 0; t < 16; ++t) {
            const int sl  = (lane & 48) + t;
            const int rcv = __shfl(rcv_l, sl);
            const int snd = __shfl(snd_l, sl);
            const float msk = __shfl(msk_l, sl);
            if (rcv != cur) {
                if (cur >= 0) {
                    float* p = agg_v + cur*384 + c*3;
                    #pragma unroll
                    for (int ntl = 0; ntl < 4; ++ntl)
                        #pragma unroll
                        for (int m = 0; m < 3; ++m)
                            unsafeAtomicAdd(p + ntl*48 + m, rv[ntl][m]);
                }
                #pragma unroll
                for (int i = 0; i < 4; ++i) { rv[i][0]=0.f; rv[i][1]=0.f; rv[i][2]=0.f; }
                cur = rcv;
            }
            const int mt = t >> 2, rr = t & 3;
            const float* vp = v_up + (snd*64 + c)*3;
            #pragma unroll
            for (int ntl = 0; ntl < 4; ++ntl) {
                const float mx = accB[mt][ntl][rr] * msk;
                #pragma unroll
                for (int m = 0; m < 3; ++m)
                    rv[ntl][m] = fmaf(vp[ntl*48 + m], mx, rv[ntl][m]);
            }
        }
        float* p = agg_v + cur*384 + c*3;
        #pragma unroll
        for (int ntl = 0; ntl < 4; ++ntl)
            #pragma unroll
            for (int m = 0; m < 3; ++m)
                unsafeAtomicAdd(p + ntl*48 + m, rv[ntl][m]);
    } else {                  // agg_v[:, 64+ntl*16+c, m] += msv * Y_m * mix3
        float rv[4][3];
        #pragma unroll
        for (int i = 0; i < 4; ++i) { rv[i][0]=0.f; rv[i][1]=0.f; rv[i][2]=0.f; }
        #pragma unroll
        for (int t = 0; t < 16; ++t) {
            const int sl  = (lane & 48) + t;
            const int rcv = __shfl(rcv_l, sl);
            const int snd = __shfl(snd_l, sl);
            const float msk = __shfl(msk_l, sl);
            const float Y0 = __shfl(Y0_l, sl), Y1 = __shfl(Y1_l, sl), Y2 = __shfl(Y2_l, sl);
            if (rcv != cur) {
                if (cur >= 0) {
                    float* p = agg_v + cur*384 + 192 + c*3;
                    #pragma unroll
                    for (int ntl = 0; ntl < 4; ++ntl)
                        #pragma unroll
                        for (int m = 0; m < 3; ++m)
                            unsafeAtomicAdd(p + ntl*48 + m, rv[ntl][m]);
                }
                #pragma unroll
                for (int i = 0; i < 4; ++i) { rv[i][0]=0.f; rv[i][1]=0.f; rv[i][2]=0.f; }
                cur = rcv;
            }
            const int mt = t >> 2, rr = t & 3;
            const float* sp = s_up + snd*64 + c;
            #pragma unroll
            for (int ntl = 0; ntl < 4; ++ntl) {
                const float mm = sp[ntl*16] * (accB[mt][ntl][rr] * msk);
                rv[ntl][0] = fmaf(mm, Y0, rv[ntl][0]);
                rv[ntl][1] = fmaf(mm, Y1, rv[ntl][1]);
                rv[ntl][2] = fmaf(mm, Y2, rv[ntl][2]);
            }
        }
        float* p = agg_v + cur*384 + 192 + c*3;
        #pragma unroll
        for (int ntl = 0; ntl < 4; ++ntl)
            #pragma unroll
            for (int m = 0; m < 3; ++m)
                unsafeAtomicAdd(p + ntl*48 + m, rv[ntl][m]);
    }
}

// ---------------------------------------------------------------------------
// K3: node down + specie skip + gating. 8 specie-sorted nodes per wave ->
// weights shared 8x; agg/ns rows are wave-uniform scalar loads.
// ---------------------------------------------------------------------------
__global__ __launch_bounds__(256) void k_node_down(
    const float* __restrict__ ns, const float* __restrict__ nv,
    const int*   __restrict__ spec_idx, const int* __restrict__ nperm,
    const float* __restrict__ Wds, const float* __restrict__ Wdv,
    const float* __restrict__ Wsks, const float* __restrict__ Wskv,
    const float* __restrict__ agg_s, const float* __restrict__ agg_v,
    float* __restrict__ out)
{
    const int lane = threadIdx.x & 63;
    const int wq   = __builtin_amdgcn_readfirstlane(threadIdx.x >> 6);
    const int base = blockIdx.x * 32 + wq * 8;

    int nd[8];
    #pragma unroll
    for (int n = 0; n < 8; ++n) nd[n] = nperm[base + n];
    if (nd[0] < 0) return;                     // wholly-dummy chunk (wave-uniform)
    const int spec = __builtin_amdgcn_readfirstlane(spec_idx[nd[0]]);

    float s0[8], s1[8], v0[8], v1[8], v2[8];
    #pragma unroll
    for (int n = 0; n < 8; ++n) { s0[n]=0.f; s1[n]=0.f; v0[n]=0.f; v1[n]=0.f; v2[n]=0.f; }

    #pragma unroll 2
    for (int i = 0; i < 128; ++i) {
        const float w0 = Wds[i*128 + lane];
        const float w1 = Wds[i*128 + 64 + lane];
        const float wv = Wdv[i*64 + lane];
        #pragma unroll
        for (int n = 0; n < 8; ++n) {
            if (nd[n] >= 0) {
                const float a = agg_s[nd[n]*128 + i] * INV_AVG;
                s0[n] = fmaf(a, w0, s0[n]);
                s1[n] = fmaf(a, w1, s1[n]);
                const float* avr = agg_v + nd[n]*384 + i*3;
                v0[n] = fmaf(avr[0] * INV_AVG, wv, v0[n]);
                v1[n] = fmaf(avr[1] * INV_AVG, wv, v1[n]);
                v2[n] = fmaf(avr[2] * INV_AVG, wv, v2[n]);
            }
        }
    }
    const float* Ws = Wsks + spec*8192;   // (64,128)
    const float* Wv = Wskv + spec*4096;   // (64,64)
    #pragma unroll 2
    for (int i = 0; i < 64; ++i) {
        const float w0 = Ws[i*128 + lane];
        const float w1 = Ws[i*128 + 64 + lane];
        const float wv = Wv[i*64 + lane];
        #pragma unroll
        for (int n = 0; n < 8; ++n) {
            if (nd[n] >= 0) {
                const float s = ns[nd[n]*64 + i];
                s0[n] = fmaf(s, w0, s0[n]);
                s1[n] = fmaf(s, w1, s1[n]);
                const float* nvr = nv + nd[n]*192 + i*3;
                v0[n] = fmaf(nvr[0], wv, v0[n]);
                v1[n] = fmaf(nvr[1], wv, v1[n]);
                v2[n] = fmaf(nvr[2], wv, v2[n]);
            }
        }
    }
    #pragma unroll
    for (int n = 0; n < 8; ++n) {
        if (nd[n] >= 0) {
            const float scal = swish_f(s0[n]);
            const float gate = swish_f(s1[n]);
            float* orow = out + nd[n]*256;
            orow[lane]            = scal;
            orow[64 + lane*3 + 0] = v0[n] * gate;
            orow[64 + lane*3 + 1] = v1[n] * gate;
            orow[64 + lane*3 + 2] = v2[n] * gate;
        }
    }
}

// ---------------------------------------------------------------------------
extern "C" void kernel_launch(void* const* d_in, const int* in_sizes, int n_in,
                              void* d_out, int out_size, void* d_ws, size_t ws_size,
                              hipStream_t stream)
{
    (void)in_sizes; (void)n_in; (void)out_size; (void)ws_size;

    const float* vectors      = (const float*)d_in[0];
    const float* node_scalars = (const float*)d_in[1];
    const float* node_vectors = (const float*)d_in[2];
    const int*   node_specie  = (const int*)d_in[3];
    const int*   senders      = (const int*)d_in[4];
    const int*   receivers    = (const int*)d_in[5];
    const float* W_skip_s     = (const float*)d_in[6];
    const float* W_skip_v     = (const float*)d_in[7];
    const float* W_up_s       = (const float*)d_in[8];
    const float* W_up_v       = (const float*)d_in[9];
    const float* W_mlp0       = (const float*)d_in[10];
    const float* W_mlp1       = (const float*)d_in[11];
    const float* W_mlp2       = (const float*)d_in[12];
    const float* W_down_s     = (const float*)d_in[13];
    const float* W_down_v     = (const float*)d_in[14];
    float* out = (float*)d_out;

    // workspace layout — peak 62,752,768 B, inside the proven <=64,000,000 B
    // envelope of rounds 2/6. nperm/scnt/scur ALIAS the perm region (perm is
    // dead after k_edge; specie sort runs after k_edge).
    float* ws    = (float*)d_ws;
    float* s_up  = ws;                        // N*64   = 1,280,000 f32
    float* v_up  = s_up + 1280000;            // N*192  = 3,840,000
    float* agg_s = v_up + 3840000;            // N*128  = 2,560,000
    float* agg_v = agg_s + 2560000;           // N*384  = 7,680,000
    int*   perm  = (int*)(agg_v + 7680000);   // E ints = 320,000
    unsigned short* W2p = (unsigned short*)(perm + 320000);   // 16384 f16 = 32KB
    int*   nperm = perm;                      // alias (perm dead post-k_edge)
    int*   scnt  = perm + NPERM_SLOTS;        // alias
    int*   scur  = scnt + 4;                  // alias
    int*   cnt    = (int*)agg_s;              // alias (dead before k_node_up)
    int*   cursor = cnt + 20000;

    // W2 fp16 B-fragment prepack
    hipLaunchKernelGGL(k_prep_w, dim3(64), dim3(256), 0, stream, W_mlp2, W2p);

    // edge counting sort by receiver
    hipLaunchKernelGGL(k_zero_cnt, dim3(79),   dim3(256),  0, stream, cnt);
    hipLaunchKernelGGL(k_hist,     dim3(1250), dim3(256),  0, stream, receivers, cnt);
    hipLaunchKernelGGL(k_scan,     dim3(1),    dim3(1024), 0, stream, cnt, cursor);
    hipLaunchKernelGGL(k_scatter,  dim3(1250), dim3(256),  0, stream, receivers, cursor, perm);

    hipLaunchKernelGGL(k_node_up, dim3(5000), dim3(256), 0, stream,
        node_scalars, node_vectors, W_up_s, W_up_v, s_up, v_up, agg_s, agg_v);
    hipLaunchKernelGGL(k_edge, dim3(5000), dim3(256), 0, stream,
        vectors, senders, receivers, perm, W_mlp0, W_mlp1, W2p,
        s_up, v_up, agg_s, agg_v);

    // specie sort (8-aligned segments) AFTER k_edge — reuses perm region
    hipLaunchKernelGGL(k_spec_init,    dim3(80), dim3(256), 0, stream, nperm, scnt);
    hipLaunchKernelGGL(k_spec_hist,    dim3(79), dim3(256), 0, stream, node_specie, scnt);
    hipLaunchKernelGGL(k_spec_off,     dim3(1),  dim3(64),  0, stream, scnt, scur);
    hipLaunchKernelGGL(k_spec_scatter, dim3(79), dim3(256), 0, stream, node_specie, scur, nperm);

    hipLaunchKernelGGL(k_node_down, dim3(NPERM_SLOTS / 32), dim3(256), 0, stream,
        node_scalars, node_vectors, node_specie, nperm, W_down_s, W_down_v,
        W_skip_s, W_skip_v, agg_s, agg_v, out);
}